// Round 1
// baseline (1335.956 us; speedup 1.0000x reference)
//
#include <hip/hip_runtime.h>

typedef unsigned short u16;
typedef _Float16 f16;
typedef __attribute__((ext_vector_type(8))) f16 f16x8;
typedef __attribute__((ext_vector_type(4))) float fx4;
typedef __attribute__((ext_vector_type(8))) u16 u16x8;
typedef __attribute__((ext_vector_type(4))) u16 u16x4;

#define SZE 8388608u  // 16384*512 elements per [B*L, D] matrix

__device__ __forceinline__ u16 f2h_bits(float x) {
  union { f16 h; u16 u; } v; v.h = (f16)x; return v.u;
}

// async global->LDS, 16B per lane; dest is wave-uniform base + lane*16.
__device__ __forceinline__ void gl2lds16(const void* g, void* l) {
  __builtin_amdgcn_global_load_lds(
      (const __attribute__((address_space(1))) unsigned int*)g,
      (__attribute__((address_space(3))) unsigned int*)l, 16, 0, 0);
}

// ---------------- kernel 1: fp32 -> fp16 convert of both inputs ------------
__global__ __launch_bounds__(256) void convert_x(const float* __restrict__ x0,
                                                 const float* __restrict__ x1,
                                                 u16* __restrict__ xh) {
  size_t i = ((size_t)blockIdx.x * 256 + threadIdx.x) * 8;
  const float* src = (i < SZE) ? (x0 + i) : (x1 + (i - SZE));
  float4 a = *(const float4*)(src);
  float4 b = *(const float4*)(src + 4);
  u16x8 o;
  o[0] = f2h_bits(a.x); o[1] = f2h_bits(a.y);
  o[2] = f2h_bits(a.z); o[3] = f2h_bits(a.w);
  o[4] = f2h_bits(b.x); o[5] = f2h_bits(b.y);
  o[6] = f2h_bits(b.z); o[7] = f2h_bits(b.w);
  *(u16x8*)(xh + i) = o;
}

// ---------------- kernel 2: W [K][N] fp32 -> Wt [N][K] fp16 ----------------
__global__ __launch_bounds__(256) void wtrans(
    const float* __restrict__ w0, const float* __restrict__ w1,
    const float* __restrict__ w2, const float* __restrict__ w3,
    const float* __restrict__ w4, const float* __restrict__ w5,
    u16* __restrict__ wt) {
  __shared__ float tile[32][33];
  const int z = blockIdx.z;
  const float* W = z == 0 ? w0 : z == 1 ? w1 : z == 2 ? w2
                 : z == 3 ? w3 : z == 4 ? w4 : w5;
  u16* WT = wt + (size_t)z * 262144u;
  const int k0 = blockIdx.x * 32, n0 = blockIdx.y * 32;
  const int tx = threadIdx.x, ty = threadIdx.y;  // 32 x 8
  for (int j = 0; j < 32; j += 8)
    tile[ty + j][tx] = W[(size_t)(k0 + ty + j) * 512 + n0 + tx];
  __syncthreads();
  for (int j = 0; j < 32; j += 8)
    WT[(size_t)(n0 + ty + j) * 512 + k0 + tx] = f2h_bits(tile[tx][ty + j]);
}

// ---------------- kernel 3: six projections, C = X*W + b -------------------
__global__ __launch_bounds__(256, 2) void proj_gemm(
    const u16* __restrict__ xh, const u16* __restrict__ wt,
    u16* __restrict__ qkv,
    const float* __restrict__ b0, const float* __restrict__ b1,
    const float* __restrict__ b2, const float* __restrict__ b3,
    const float* __restrict__ b4, const float* __restrict__ b5) {
  const int proj = blockIdx.z;
  const u16* X = xh + (proj < 3 ? 0u : SZE);
  const u16* W = wt + (size_t)proj * 262144u;
  u16* out = qkv + (size_t)proj * SZE;
  const float* bias = proj == 0 ? b0 : proj == 1 ? b1 : proj == 2 ? b2
                    : proj == 3 ? b3 : proj == 4 ? b4 : b5;
  const int m0 = blockIdx.x * 128, n0 = blockIdx.y * 128;
  const int t = threadIdx.x, lane = t & 63, w = t >> 6;
  const int wr = w >> 1, wc = w & 1, ml = lane & 15, q = lane >> 4;
  __shared__ u16 sA[4096], sB[4096];
  fx4 acc[4][4] = {};
  for (int k0 = 0; k0 < 512; k0 += 32) {
    for (int r = 0; r < 2; ++r) {
      int c = r * 256 + t;
      int cq = c >> 7, cm = c & 127;
      gl2lds16(X + (size_t)(m0 + cm) * 512 + (k0 + cq * 8), sA + c * 8);
      gl2lds16(W + (size_t)(n0 + cm) * 512 + (k0 + cq * 8), sB + c * 8);
    }
    __syncthreads();
    f16x8 af[4], bf[4];
    for (int i = 0; i < 4; ++i) {
      af[i] = *(const f16x8*)(sA + (q * 128 + wr * 64 + i * 16 + ml) * 8);
      bf[i] = *(const f16x8*)(sB + (q * 128 + wc * 64 + i * 16 + ml) * 8);
    }
    for (int i = 0; i < 4; ++i)
      for (int j = 0; j < 4; ++j)
        acc[i][j] = __builtin_amdgcn_mfma_f32_16x16x32_f16(af[i], bf[j],
                                                           acc[i][j], 0, 0, 0);
    __syncthreads();
  }
  const bool vtrans = (proj % 3) == 2;
  for (int j = 0; j < 4; ++j) {
    const int n = n0 + wc * 64 + j * 16 + ml;
    const float bv = bias[n];
    for (int i = 0; i < 4; ++i) {
      const int mb = m0 + wr * 64 + i * 16 + q * 4;
      if (!vtrans) {
        for (int r = 0; r < 4; ++r)
          out[(size_t)(mb + r) * 512 + n] = f2h_bits(acc[i][j][r] + bv);
      } else {
        const int bb = mb >> 11, l = mb & 2047;
        u16x4 pk;
        for (int r = 0; r < 4; ++r) pk[r] = f2h_bits(acc[i][j][r] + bv);
        *(u16x4*)(out + ((size_t)bb * 512 + n) * 2048 + l) = pk;
      }
    }
  }
}

// ---------------- kernel 4: flash cross-attention v6 -----------------------
// R=32 rows/wave, 4 waves x 256 threads, same 128 queries/block, 256 blocks.
// Each K-fragment and V-fragment ds_read now feeds TWO MFMAs (rowblocks 0/1):
// LDS traffic per CU per iter halves (512KB -> 256KB, below the 2480-cyc MFMA
// floor), and per-wave MFMA ILP doubles (4 indep QK chains, 64 indep PV MFMAs).
// Occupancy drops to 1 wave/SIMD by design (acc 256 + qf 128 VGPR); the wave
// is self-sufficient: Q resident in regs, P in a wave-private LDS slab (no
// barrier), K/V double-buffered with a single end-of-iter barrier whose
// staging cover is the whole iteration.
__global__ __launch_bounds__(256, 1) void attn_kernel(const u16* __restrict__ qkv,
                                                      float* __restrict__ out) {
  const int t = threadIdx.x, lane = t & 63, w = t >> 6;  // w in 0..3
  const int ml = lane & 15, q = lane >> 4;
  // XCD swizzle: xcd = n&7 owns (b,tt) groups {2*xcd, 2*xcd+1}
  const int n = blockIdx.x;
  const int xcd = n & 7, slot = n >> 3;
  const int g = xcd * 2 + (slot >> 4);
  const int qt = slot & 15;
  const int b = g >> 1, tt = g & 1;

  const u16* Q  = qkv + (tt ? (size_t)3 * SZE : (size_t)0);
  const u16* K  = qkv + (tt ? (size_t)1 * SZE : (size_t)4 * SZE);
  const u16* Vt = qkv + (tt ? (size_t)5 * SZE : (size_t)2 * SZE);
  float* O = out + (tt ? (size_t)SZE : (size_t)0) +
             ((size_t)b * 2048 + qt * 128) * 512;
  const u16* Qb = Q + ((size_t)b * 2048 + qt * 128) * 512;
  const u16* Kb = K + (size_t)b * 2048 * 512;
  const u16* Vb = Vt + (size_t)b * 512 * 2048;  // [D][L]

  __shared__ u16 sK[2][16384];   // 2 x 32KB, chunk p: [dchunk(64)][key(32)]
  __shared__ u16 sV[2][16384];   // 2 x 32KB, chunk p: [kc(4)][d(512)]
  __shared__ u16 sP[4 * 1280];   // per-wave 32 rows x stride 40

  // Q A-frags for this wave's 32 rows (128 VGPR, resident all 64 iters)
  f16x8 qf0[16], qf1[16];
  {
    const u16* qrow0 = Qb + (size_t)(w * 32 + ml) * 512 + q * 8;
    const u16* qrow1 = qrow0 + 16 * 512;
#pragma unroll
    for (int ks = 0; ks < 16; ++ks) {
      qf0[ks] = *(const f16x8*)(qrow0 + ks * 32);
      qf1[ks] = *(const f16x8*)(qrow1 + ks * 32);
    }
  }

  fx4 acc0[32] = {}, acc1[32] = {};  // rows q*4+r of rowblock, col nj*16+ml
  fx4 mrun0 = {-3.0e38f, -3.0e38f, -3.0e38f, -3.0e38f};
  fx4 mrun1 = {-3.0e38f, -3.0e38f, -3.0e38f, -3.0e38f};
  fx4 lrun0 = {0.f, 0.f, 0.f, 0.f};
  fx4 lrun1 = {0.f, 0.f, 0.f, 0.f};
  u16* wp = sP + w * 1280;

  // prestage K[0], V[0] into buffer 0
#pragma unroll
  for (int r = 0; r < 8; ++r) {
    int p = r * 256 + t;
    gl2lds16(Kb + (size_t)(p & 31) * 512 + (p >> 5) * 8, sK[0] + p * 8);
    gl2lds16(Vb + (size_t)(p & 511) * 2048 + (p >> 9) * 8, sV[0] + p * 8);
  }
  __syncthreads();

  for (int it = 0; it < 64; ++it) {
    const int c = it & 1;
    const int k0 = it * 32;
    const u16* sKc = sK[c];
    const u16* sVc = sV[c];
    // ---- stage K[it+1], V[it+1] into other buffer; drained at THIS iter's
    //      single end barrier (cover = entire iteration) ----
    if (it < 63) {
      const u16* Kn = Kb + (size_t)(k0 + 32) * 512;
      const u16* Vn = Vb + (size_t)(k0 + 32);
#pragma unroll
      for (int r = 0; r < 8; ++r) {
        int p = r * 256 + t;
        gl2lds16(Kn + (size_t)(p & 31) * 512 + (p >> 5) * 8, sK[c ^ 1] + p * 8);
        gl2lds16(Vn + (size_t)(p & 511) * 2048 + (p >> 9) * 8, sV[c ^ 1] + p * 8);
      }
    }
    // ---- QK^T: 32 rows x 32 keys; each kf feeds 2 MFMAs ----
    fx4 s00 = {0.f, 0.f, 0.f, 0.f}, s01 = {0.f, 0.f, 0.f, 0.f};
    fx4 s10 = {0.f, 0.f, 0.f, 0.f}, s11 = {0.f, 0.f, 0.f, 0.f};
#pragma unroll
    for (int ks = 0; ks < 16; ++ks) {
      f16x8 kf0 = *(const f16x8*)(sKc + ((ks * 4 + q) * 32 + ml) * 8);
      f16x8 kf1 = *(const f16x8*)(sKc + ((ks * 4 + q) * 32 + 16 + ml) * 8);
      s00 = __builtin_amdgcn_mfma_f32_16x16x32_f16(qf0[ks], kf0, s00, 0, 0, 0);
      s01 = __builtin_amdgcn_mfma_f32_16x16x32_f16(qf0[ks], kf1, s01, 0, 0, 0);
      s10 = __builtin_amdgcn_mfma_f32_16x16x32_f16(qf1[ks], kf0, s10, 0, 0, 0);
      s11 = __builtin_amdgcn_mfma_f32_16x16x32_f16(qf1[ks], kf1, s11, 0, 0, 0);
    }
    // ---- online softmax, state in regs (rows = quad lanes q*4+r) ----
    bool need0 = false, need1 = false;
    fx4 al0, al1;
    {  // rowblock 0
      fx4 mx, sm;
#pragma unroll
      for (int r = 0; r < 4; ++r) mx[r] = fmaxf(s00[r], s01[r]);
#pragma unroll
      for (int d = 1; d < 16; d <<= 1) {
        mx[0] = fmaxf(mx[0], __shfl_xor(mx[0], d));
        mx[1] = fmaxf(mx[1], __shfl_xor(mx[1], d));
        mx[2] = fmaxf(mx[2], __shfl_xor(mx[2], d));
        mx[3] = fmaxf(mx[3], __shfl_xor(mx[3], d));
      }
#pragma unroll
      for (int r = 0; r < 4; ++r) {
        float mn = fmaxf(mrun0[r], mx[r]);
        al0[r] = __expf(mrun0[r] - mn);
        mrun0[r] = mn;
        s00[r] = __expf(s00[r] - mn);
        s01[r] = __expf(s01[r] - mn);
        sm[r] = s00[r] + s01[r];
        need0 |= (al0[r] != 1.0f);
      }
#pragma unroll
      for (int d = 1; d < 16; d <<= 1) {
        sm[0] += __shfl_xor(sm[0], d);
        sm[1] += __shfl_xor(sm[1], d);
        sm[2] += __shfl_xor(sm[2], d);
        sm[3] += __shfl_xor(sm[3], d);
      }
#pragma unroll
      for (int r = 0; r < 4; ++r) lrun0[r] = al0[r] * lrun0[r] + sm[r];
#pragma unroll
      for (int r = 0; r < 4; ++r) {
        wp[(q * 4 + r) * 40 + ml] = f2h_bits(s00[r]);
        wp[(q * 4 + r) * 40 + 16 + ml] = f2h_bits(s01[r]);
      }
    }
    {  // rowblock 1
      fx4 mx, sm;
#pragma unroll
      for (int r = 0; r < 4; ++r) mx[r] = fmaxf(s10[r], s11[r]);
#pragma unroll
      for (int d = 1; d < 16; d <<= 1) {
        mx[0] = fmaxf(mx[0], __shfl_xor(mx[0], d));
        mx[1] = fmaxf(mx[1], __shfl_xor(mx[1], d));
        mx[2] = fmaxf(mx[2], __shfl_xor(mx[2], d));
        mx[3] = fmaxf(mx[3], __shfl_xor(mx[3], d));
      }
#pragma unroll
      for (int r = 0; r < 4; ++r) {
        float mn = fmaxf(mrun1[r], mx[r]);
        al1[r] = __expf(mrun1[r] - mn);
        mrun1[r] = mn;
        s10[r] = __expf(s10[r] - mn);
        s11[r] = __expf(s11[r] - mn);
        sm[r] = s10[r] + s11[r];
        need1 |= (al1[r] != 1.0f);
      }
#pragma unroll
      for (int d = 1; d < 16; d <<= 1) {
        sm[0] += __shfl_xor(sm[0], d);
        sm[1] += __shfl_xor(sm[1], d);
        sm[2] += __shfl_xor(sm[2], d);
        sm[3] += __shfl_xor(sm[3], d);
      }
#pragma unroll
      for (int r = 0; r < 4; ++r) lrun1[r] = al1[r] * lrun1[r] + sm[r];
#pragma unroll
      for (int r = 0; r < 4; ++r) {
        wp[(16 + q * 4 + r) * 40 + ml] = f2h_bits(s10[r]);
        wp[(16 + q * 4 + r) * 40 + 16 + ml] = f2h_bits(s11[r]);
      }
    }
    // ---- rescale acc (per rowblock, skip when no row saw a new max);
    //      also covers the P ds_write -> pf ds_read latency ----
    if (__any(need0)) {
#pragma unroll
      for (int nj = 0; nj < 32; ++nj) {
        acc0[nj][0] *= al0[0]; acc0[nj][1] *= al0[1];
        acc0[nj][2] *= al0[2]; acc0[nj][3] *= al0[3];
      }
    }
    if (__any(need1)) {
#pragma unroll
      for (int nj = 0; nj < 32; ++nj) {
        acc1[nj][0] *= al1[0]; acc1[nj][1] *= al1[1];
        acc1[nj][2] *= al1[2]; acc1[nj][3] *= al1[3];
      }
    }
    // ---- P frags (wave-private slab: same-wave lgkm ordering, no barrier) --
    f16x8 pf0 = *(const f16x8*)(wp + ml * 40 + q * 8);
    f16x8 pf1 = *(const f16x8*)(wp + (16 + ml) * 40 + q * 8);
    // ---- PV over all 512 d; each vf feeds 2 MFMAs ----
#pragma unroll
    for (int nj = 0; nj < 32; ++nj) {
      f16x8 vf = *(const f16x8*)(sVc + (q * 512 + nj * 16 + ml) * 8);
      acc0[nj] = __builtin_amdgcn_mfma_f32_16x16x32_f16(pf0, vf, acc0[nj], 0, 0, 0);
      acc1[nj] = __builtin_amdgcn_mfma_f32_16x16x32_f16(pf1, vf, acc1[nj], 0, 0, 0);
    }
    __syncthreads();  // single barrier: drains next-iter staging + buffer flip
  }
  // ---- epilogue: O = acc / l (all wave-private) ----
  fx4 linv0, linv1;
#pragma unroll
  for (int r = 0; r < 4; ++r) {
    linv0[r] = 1.0f / lrun0[r];
    linv1[r] = 1.0f / lrun1[r];
  }
  float* Ob0 = O + (size_t)(w * 32 + q * 4) * 512 + ml;
  float* Ob1 = Ob0 + (size_t)16 * 512;
#pragma unroll
  for (int nj = 0; nj < 32; ++nj) {
#pragma unroll
    for (int r = 0; r < 4; ++r) {
      Ob0[(size_t)r * 512 + nj * 16] = acc0[nj][r] * linv0[r];
      Ob1[(size_t)r * 512 + nj * 16] = acc1[nj][r] * linv1[r];
    }
  }
}

extern "C" void kernel_launch(void* const* d_in, const int* in_sizes, int n_in,
                              void* d_out, int out_size, void* d_ws, size_t ws_size,
                              hipStream_t stream) {
  // ws layout (u16 elems): [xh: 2*SZE][wt: 6*512*512][qkv: 6*SZE]
  //   qkv order: 0=Qr 1=Kr 2=Vr^T 3=Qh 4=Kh 5=Vh^T
  u16* ws = (u16*)d_ws;
  u16* xh = ws;
  u16* wt = ws + 16777216u;            // 2*SZE
  u16* qkv = ws + 18350080u;           // 2*SZE + 6*262144

  convert_x<<<8192, 256, 0, stream>>>((const float*)d_in[0],
                                      (const float*)d_in[1], xh);
  wtrans<<<dim3(16, 16, 6), dim3(32, 8), 0, stream>>>(
      (const float*)d_in[2], (const float*)d_in[4], (const float*)d_in[6],
      (const float*)d_in[8], (const float*)d_in[10], (const float*)d_in[12], wt);
  proj_gemm<<<dim3(128, 4, 6), 256, 0, stream>>>(
      xh, wt, qkv,
      (const float*)d_in[3], (const float*)d_in[5], (const float*)d_in[7],
      (const float*)d_in[9], (const float*)d_in[11], (const float*)d_in[13]);
  attn_kernel<<<256, 256, 0, stream>>>(qkv, (float*)d_out);
}

// Round 2
// 970.309 us; speedup vs baseline: 1.3768x; 1.3768x over previous
//
#include <hip/hip_runtime.h>

typedef unsigned short u16;
typedef _Float16 f16;
typedef __attribute__((ext_vector_type(8))) f16 f16x8;
typedef __attribute__((ext_vector_type(4))) float fx4;
typedef __attribute__((ext_vector_type(8))) u16 u16x8;
typedef __attribute__((ext_vector_type(4))) u16 u16x4;

#define SZE 8388608u  // 16384*512 elements per [B*L, D] matrix

__device__ __forceinline__ u16 f2h_bits(float x) {
  union { f16 h; u16 u; } v; v.h = (f16)x; return v.u;
}

// async global->LDS, 16B per lane; dest is wave-uniform base + lane*16.
__device__ __forceinline__ void gl2lds16(const void* g, void* l) {
  __builtin_amdgcn_global_load_lds(
      (const __attribute__((address_space(1))) unsigned int*)g,
      (__attribute__((address_space(3))) unsigned int*)l, 16, 0, 0);
}

// ---------------- kernel 1: fp32 -> fp16 convert of both inputs ------------
__global__ __launch_bounds__(256) void convert_x(const float* __restrict__ x0,
                                                 const float* __restrict__ x1,
                                                 u16* __restrict__ xh) {
  size_t i = ((size_t)blockIdx.x * 256 + threadIdx.x) * 8;
  const float* src = (i < SZE) ? (x0 + i) : (x1 + (i - SZE));
  float4 a = *(const float4*)(src);
  float4 b = *(const float4*)(src + 4);
  u16x8 o;
  o[0] = f2h_bits(a.x); o[1] = f2h_bits(a.y);
  o[2] = f2h_bits(a.z); o[3] = f2h_bits(a.w);
  o[4] = f2h_bits(b.x); o[5] = f2h_bits(b.y);
  o[6] = f2h_bits(b.z); o[7] = f2h_bits(b.w);
  *(u16x8*)(xh + i) = o;
}

// ---------------- kernel 2: W [K][N] fp32 -> Wt [N][K] fp16 ----------------
__global__ __launch_bounds__(256) void wtrans(
    const float* __restrict__ w0, const float* __restrict__ w1,
    const float* __restrict__ w2, const float* __restrict__ w3,
    const float* __restrict__ w4, const float* __restrict__ w5,
    u16* __restrict__ wt) {
  __shared__ float tile[32][33];
  const int z = blockIdx.z;
  const float* W = z == 0 ? w0 : z == 1 ? w1 : z == 2 ? w2
                 : z == 3 ? w3 : z == 4 ? w4 : w5;
  u16* WT = wt + (size_t)z * 262144u;
  const int k0 = blockIdx.x * 32, n0 = blockIdx.y * 32;
  const int tx = threadIdx.x, ty = threadIdx.y;  // 32 x 8
  for (int j = 0; j < 32; j += 8)
    tile[ty + j][tx] = W[(size_t)(k0 + ty + j) * 512 + n0 + tx];
  __syncthreads();
  for (int j = 0; j < 32; j += 8)
    WT[(size_t)(n0 + ty + j) * 512 + k0 + tx] = f2h_bits(tile[tx][ty + j]);
}

// ---------------- kernel 3: six projections, C = X*W + b -------------------
__global__ __launch_bounds__(256, 2) void proj_gemm(
    const u16* __restrict__ xh, const u16* __restrict__ wt,
    u16* __restrict__ qkv,
    const float* __restrict__ b0, const float* __restrict__ b1,
    const float* __restrict__ b2, const float* __restrict__ b3,
    const float* __restrict__ b4, const float* __restrict__ b5) {
  const int proj = blockIdx.z;
  const u16* X = xh + (proj < 3 ? 0u : SZE);
  const u16* W = wt + (size_t)proj * 262144u;
  u16* out = qkv + (size_t)proj * SZE;
  const float* bias = proj == 0 ? b0 : proj == 1 ? b1 : proj == 2 ? b2
                    : proj == 3 ? b3 : proj == 4 ? b4 : b5;
  const int m0 = blockIdx.x * 128, n0 = blockIdx.y * 128;
  const int t = threadIdx.x, lane = t & 63, w = t >> 6;
  const int wr = w >> 1, wc = w & 1, ml = lane & 15, q = lane >> 4;
  __shared__ u16 sA[4096], sB[4096];
  fx4 acc[4][4] = {};
  for (int k0 = 0; k0 < 512; k0 += 32) {
    for (int r = 0; r < 2; ++r) {
      int c = r * 256 + t;
      int cq = c >> 7, cm = c & 127;
      gl2lds16(X + (size_t)(m0 + cm) * 512 + (k0 + cq * 8), sA + c * 8);
      gl2lds16(W + (size_t)(n0 + cm) * 512 + (k0 + cq * 8), sB + c * 8);
    }
    __syncthreads();
    f16x8 af[4], bf[4];
    for (int i = 0; i < 4; ++i) {
      af[i] = *(const f16x8*)(sA + (q * 128 + wr * 64 + i * 16 + ml) * 8);
      bf[i] = *(const f16x8*)(sB + (q * 128 + wc * 64 + i * 16 + ml) * 8);
    }
    for (int i = 0; i < 4; ++i)
      for (int j = 0; j < 4; ++j)
        acc[i][j] = __builtin_amdgcn_mfma_f32_16x16x32_f16(af[i], bf[j],
                                                           acc[i][j], 0, 0, 0);
    __syncthreads();
  }
  const bool vtrans = (proj % 3) == 2;
  for (int j = 0; j < 4; ++j) {
    const int n = n0 + wc * 64 + j * 16 + ml;
    const float bv = bias[n];
    for (int i = 0; i < 4; ++i) {
      const int mb = m0 + wr * 64 + i * 16 + q * 4;
      if (!vtrans) {
        for (int r = 0; r < 4; ++r)
          out[(size_t)(mb + r) * 512 + n] = f2h_bits(acc[i][j][r] + bv);
      } else {
        const int bb = mb >> 11, l = mb & 2047;
        u16x4 pk;
        for (int r = 0; r < 4; ++r) pk[r] = f2h_bits(acc[i][j][r] + bv);
        *(u16x4*)(out + ((size_t)bb * 512 + n) * 2048 + l) = pk;
      }
    }
  }
}

// ---------------- kernel 4: flash cross-attention v7 -----------------------
// Back to the proven R=16 / 8-wave structure (v5, 310us). ONE change: V
// fragments are read directly from global (the V^T stream is L2-resident --
// all 16 blocks of a (b,tt) group sit on one XCD via the swizzle, and qkv
// (96MB) is LLC-resident; FETCH_SIZE=49MB confirmed). This moves 32 of the
// ~70 LDS ops/wave/iter off the 58%-busy LDS pipe onto the ~5%-busy VMEM
// pipe: LDS ~6700 -> ~3900 cyc/iter/CU, VMEM ~4400 cyc/iter/CU (26 TB/s
// aggregate L2, under the 34.5 TB/s ceiling) -- different pipes, overlapped
// by the single-barrier wave drift. Staging per iter halves (K only), so the
// end-barrier vmcnt drain tail shrinks too. Register demand unchanged
// (~130 + compiler V lookahead), no spill (the R=32 lesson).
__global__ __launch_bounds__(512, 2) void attn_kernel(const u16* __restrict__ qkv,
                                                      float* __restrict__ out) {
  const int t = threadIdx.x, lane = t & 63, w = t >> 6;  // w in 0..7
  const int ml = lane & 15, q = lane >> 4;
  // XCD swizzle: xcd = n&7 owns (b,tt) groups {2*xcd, 2*xcd+1}
  const int n = blockIdx.x;
  const int xcd = n & 7, slot = n >> 3;
  const int g = xcd * 2 + (slot >> 4);
  const int qt = slot & 15;
  const int b = g >> 1, tt = g & 1;

  const u16* Q  = qkv + (tt ? (size_t)3 * SZE : (size_t)0);
  const u16* K  = qkv + (tt ? (size_t)1 * SZE : (size_t)4 * SZE);
  const u16* Vt = qkv + (tt ? (size_t)5 * SZE : (size_t)2 * SZE);
  float* O = out + (tt ? (size_t)SZE : (size_t)0) +
             ((size_t)b * 2048 + qt * 128) * 512;
  const u16* Qb = Q + ((size_t)b * 2048 + qt * 128) * 512;
  const u16* Kb = K + (size_t)b * 2048 * 512;
  const u16* Vb = Vt + (size_t)b * 512 * 2048;  // [D][L]

  __shared__ u16 sK[2][16384];   // 2 x 32KB, chunk p: [dchunk(64)][key(32)]
  __shared__ u16 sP[8 * 640];    // per-wave 16 rows x stride 40

  // Q A-frags for this wave's 16 rows (64 VGPR, resident all 64 iters)
  f16x8 qf[16];
  {
    const u16* qrow = Qb + (size_t)(w * 16 + ml) * 512 + q * 8;
#pragma unroll
    for (int ks = 0; ks < 16; ++ks) qf[ks] = *(const f16x8*)(qrow + ks * 32);
  }

  fx4 acc[32] = {};  // rows q*4+r (of wave's 16), col nj*16+ml  (128 VGPR)
  fx4 mrun = {-3.0e38f, -3.0e38f, -3.0e38f, -3.0e38f};
  fx4 lrun = {0.f, 0.f, 0.f, 0.f};
  u16* wp = sP + w * 640;

  // prestage K[0] into buffer 0
#pragma unroll
  for (int r = 0; r < 4; ++r) {
    int p = r * 512 + t;
    gl2lds16(Kb + (size_t)(p & 31) * 512 + (p >> 5) * 8, sK[0] + p * 8);
  }
  __syncthreads();

  for (int it = 0; it < 64; ++it) {
    const int c = it & 1;
    const int k0 = it * 32;
    const u16* sKc = sK[c];
    // per-lane V^T base for this iter's 32 keys (global, L2-resident)
    const u16* vg = Vb + (size_t)ml * 2048 + (k0 + q * 8);
    // ---- stage K[it+1] into other buffer; drained at THIS iter's single
    //      end barrier (cover = entire iteration) ----
    if (it < 63) {
      const u16* Kn = Kb + (size_t)(k0 + 32) * 512;
#pragma unroll
      for (int r = 0; r < 4; ++r) {
        int p = r * 512 + t;
        gl2lds16(Kn + (size_t)(p & 31) * 512 + (p >> 5) * 8, sK[c ^ 1] + p * 8);
      }
    }
    // ---- QK^T: this wave's 16 rows x 32 keys ----
    fx4 s0 = {0.f, 0.f, 0.f, 0.f}, s1 = {0.f, 0.f, 0.f, 0.f};
#pragma unroll
    for (int ks = 0; ks < 16; ++ks) {
      f16x8 kf0 = *(const f16x8*)(sKc + ((ks * 4 + q) * 32 + ml) * 8);
      f16x8 kf1 = *(const f16x8*)(sKc + ((ks * 4 + q) * 32 + 16 + ml) * 8);
      s0 = __builtin_amdgcn_mfma_f32_16x16x32_f16(qf[ks], kf0, s0, 0, 0, 0);
      s1 = __builtin_amdgcn_mfma_f32_16x16x32_f16(qf[ks], kf1, s1, 0, 0, 0);
    }
    // ---- online softmax, state in regs (rows = quad lanes q*4+r) ----
    fx4 mx, alpha, p0, p1, sm;
#pragma unroll
    for (int r = 0; r < 4; ++r) mx[r] = fmaxf(s0[r], s1[r]);
#pragma unroll
    for (int d = 1; d < 16; d <<= 1) {
      mx[0] = fmaxf(mx[0], __shfl_xor(mx[0], d));
      mx[1] = fmaxf(mx[1], __shfl_xor(mx[1], d));
      mx[2] = fmaxf(mx[2], __shfl_xor(mx[2], d));
      mx[3] = fmaxf(mx[3], __shfl_xor(mx[3], d));
    }
    bool need = false;
#pragma unroll
    for (int r = 0; r < 4; ++r) {
      float mn = fmaxf(mrun[r], mx[r]);
      alpha[r] = __expf(mrun[r] - mn);
      mrun[r] = mn;
      p0[r] = __expf(s0[r] - mn);
      p1[r] = __expf(s1[r] - mn);
      sm[r] = p0[r] + p1[r];
      need |= (alpha[r] != 1.0f);
    }
#pragma unroll
    for (int d = 1; d < 16; d <<= 1) {
      sm[0] += __shfl_xor(sm[0], d);
      sm[1] += __shfl_xor(sm[1], d);
      sm[2] += __shfl_xor(sm[2], d);
      sm[3] += __shfl_xor(sm[3], d);
    }
#pragma unroll
    for (int r = 0; r < 4; ++r) lrun[r] = alpha[r] * lrun[r] + sm[r];
    // ---- P -> wave-private slab (no barrier: same-wave lgkm ordering) ----
#pragma unroll
    for (int r = 0; r < 4; ++r) {
      wp[(q * 4 + r) * 40 + ml] = f2h_bits(p0[r]);
      wp[(q * 4 + r) * 40 + 16 + ml] = f2h_bits(p1[r]);
    }
    // ---- rescale acc (skip when no row saw a new max) ----
    if (__any(need)) {
#pragma unroll
      for (int nj = 0; nj < 32; ++nj) {
        acc[nj][0] *= alpha[0]; acc[nj][1] *= alpha[1];
        acc[nj][2] *= alpha[2]; acc[nj][3] *= alpha[3];
      }
    }
    f16x8 pf = *(const f16x8*)(wp + ml * 40 + q * 8);
    // ---- PV over all 512 d; V streamed from L2 (global), one 16B load
    //      per MFMA, independent of LDS pipe ----
#pragma unroll
    for (int nj = 0; nj < 32; ++nj) {
      f16x8 vf = *(const f16x8*)(vg + (size_t)nj * 32768);
      acc[nj] = __builtin_amdgcn_mfma_f32_16x16x32_f16(pf, vf, acc[nj], 0, 0, 0);
    }
    __syncthreads();  // single barrier: drains next-iter K staging + flip
  }
  // ---- epilogue: O = acc / l (all wave-private) ----
  fx4 linv;
#pragma unroll
  for (int r = 0; r < 4; ++r) linv[r] = 1.0f / lrun[r];
  float* Ob = O + (size_t)(w * 16 + q * 4) * 512 + ml;
#pragma unroll
  for (int nj = 0; nj < 32; ++nj) {
#pragma unroll
    for (int r = 0; r < 4; ++r)
      Ob[(size_t)r * 512 + nj * 16] = acc[nj][r] * linv[r];
  }
}

extern "C" void kernel_launch(void* const* d_in, const int* in_sizes, int n_in,
                              void* d_out, int out_size, void* d_ws, size_t ws_size,
                              hipStream_t stream) {
  // ws layout (u16 elems): [xh: 2*SZE][wt: 6*512*512][qkv: 6*SZE]
  //   qkv order: 0=Qr 1=Kr 2=Vr^T 3=Qh 4=Kh 5=Vh^T
  u16* ws = (u16*)d_ws;
  u16* xh = ws;
  u16* wt = ws + 16777216u;            // 2*SZE
  u16* qkv = ws + 18350080u;           // 2*SZE + 6*262144

  convert_x<<<8192, 256, 0, stream>>>((const float*)d_in[0],
                                      (const float*)d_in[1], xh);
  wtrans<<<dim3(16, 16, 6), dim3(32, 8), 0, stream>>>(
      (const float*)d_in[2], (const float*)d_in[4], (const float*)d_in[6],
      (const float*)d_in[8], (const float*)d_in[10], (const float*)d_in[12], wt);
  proj_gemm<<<dim3(128, 4, 6), 256, 0, stream>>>(
      xh, wt, qkv,
      (const float*)d_in[3], (const float*)d_in[5], (const float*)d_in[7],
      (const float*)d_in[9], (const float*)d_in[11], (const float*)d_in[13]);
  attn_kernel<<<256, 512, 0, stream>>>(qkv, (float*)d_out);
}

// Round 3
// 797.690 us; speedup vs baseline: 1.6748x; 1.2164x over previous
//
#include <hip/hip_runtime.h>

typedef unsigned short u16;
typedef _Float16 f16;
typedef __attribute__((ext_vector_type(8))) f16 f16x8;
typedef __attribute__((ext_vector_type(4))) float fx4;
typedef __attribute__((ext_vector_type(8))) u16 u16x8;
typedef __attribute__((ext_vector_type(4))) u16 u16x4;

#define SZE 8388608u  // 16384*512 elements per [B*L, D] matrix

__device__ __forceinline__ u16 f2h_bits(float x) {
  union { f16 h; u16 u; } v; v.h = (f16)x; return v.u;
}

// async global->LDS, 16B per lane; dest is wave-uniform base + lane*16.
__device__ __forceinline__ void gl2lds16(const void* g, void* l) {
  __builtin_amdgcn_global_load_lds(
      (const __attribute__((address_space(1))) unsigned int*)g,
      (__attribute__((address_space(3))) unsigned int*)l, 16, 0, 0);
}

// ---------------- kernel 1: fp32 -> fp16 convert of both inputs ------------
__global__ __launch_bounds__(256) void convert_x(const float* __restrict__ x0,
                                                 const float* __restrict__ x1,
                                                 u16* __restrict__ xh) {
  size_t i = ((size_t)blockIdx.x * 256 + threadIdx.x) * 8;
  const float* src = (i < SZE) ? (x0 + i) : (x1 + (i - SZE));
  float4 a = *(const float4*)(src);
  float4 b = *(const float4*)(src + 4);
  u16x8 o;
  o[0] = f2h_bits(a.x); o[1] = f2h_bits(a.y);
  o[2] = f2h_bits(a.z); o[3] = f2h_bits(a.w);
  o[4] = f2h_bits(b.x); o[5] = f2h_bits(b.y);
  o[6] = f2h_bits(b.z); o[7] = f2h_bits(b.w);
  *(u16x8*)(xh + i) = o;
}

// ---------------- kernel 2: W [K][N] fp32 -> Wt [N][K] fp16 ----------------
__global__ __launch_bounds__(256) void wtrans(
    const float* __restrict__ w0, const float* __restrict__ w1,
    const float* __restrict__ w2, const float* __restrict__ w3,
    const float* __restrict__ w4, const float* __restrict__ w5,
    u16* __restrict__ wt) {
  __shared__ float tile[32][33];
  const int z = blockIdx.z;
  const float* W = z == 0 ? w0 : z == 1 ? w1 : z == 2 ? w2
                 : z == 3 ? w3 : z == 4 ? w4 : w5;
  u16* WT = wt + (size_t)z * 262144u;
  const int k0 = blockIdx.x * 32, n0 = blockIdx.y * 32;
  const int tx = threadIdx.x, ty = threadIdx.y;  // 32 x 8
  for (int j = 0; j < 32; j += 8)
    tile[ty + j][tx] = W[(size_t)(k0 + ty + j) * 512 + n0 + tx];
  __syncthreads();
  for (int j = 0; j < 32; j += 8)
    WT[(size_t)(n0 + ty + j) * 512 + k0 + tx] = f2h_bits(tile[tx][ty + j]);
}

// ---------------- kernel 3: six projections, C = X*W + b -------------------
__global__ __launch_bounds__(256, 2) void proj_gemm(
    const u16* __restrict__ xh, const u16* __restrict__ wt,
    u16* __restrict__ qkv,
    const float* __restrict__ b0, const float* __restrict__ b1,
    const float* __restrict__ b2, const float* __restrict__ b3,
    const float* __restrict__ b4, const float* __restrict__ b5) {
  const int proj = blockIdx.z;
  const u16* X = xh + (proj < 3 ? 0u : SZE);
  const u16* W = wt + (size_t)proj * 262144u;
  u16* out = qkv + (size_t)proj * SZE;
  const float* bias = proj == 0 ? b0 : proj == 1 ? b1 : proj == 2 ? b2
                    : proj == 3 ? b3 : proj == 4 ? b4 : b5;
  const int m0 = blockIdx.x * 128, n0 = blockIdx.y * 128;
  const int t = threadIdx.x, lane = t & 63, w = t >> 6;
  const int wr = w >> 1, wc = w & 1, ml = lane & 15, q = lane >> 4;
  __shared__ u16 sA[4096], sB[4096];
  fx4 acc[4][4] = {};
  for (int k0 = 0; k0 < 512; k0 += 32) {
    for (int r = 0; r < 2; ++r) {
      int c = r * 256 + t;
      int cq = c >> 7, cm = c & 127;
      gl2lds16(X + (size_t)(m0 + cm) * 512 + (k0 + cq * 8), sA + c * 8);
      gl2lds16(W + (size_t)(n0 + cm) * 512 + (k0 + cq * 8), sB + c * 8);
    }
    __syncthreads();
    f16x8 af[4], bf[4];
    for (int i = 0; i < 4; ++i) {
      af[i] = *(const f16x8*)(sA + (q * 128 + wr * 64 + i * 16 + ml) * 8);
      bf[i] = *(const f16x8*)(sB + (q * 128 + wc * 64 + i * 16 + ml) * 8);
    }
    for (int i = 0; i < 4; ++i)
      for (int j = 0; j < 4; ++j)
        acc[i][j] = __builtin_amdgcn_mfma_f32_16x16x32_f16(af[i], bf[j],
                                                           acc[i][j], 0, 0, 0);
    __syncthreads();
  }
  const bool vtrans = (proj % 3) == 2;
  for (int j = 0; j < 4; ++j) {
    const int n = n0 + wc * 64 + j * 16 + ml;
    const float bv = bias[n];
    for (int i = 0; i < 4; ++i) {
      const int mb = m0 + wr * 64 + i * 16 + q * 4;
      if (!vtrans) {
        for (int r = 0; r < 4; ++r)
          out[(size_t)(mb + r) * 512 + n] = f2h_bits(acc[i][j][r] + bv);
      } else {
        const int bb = mb >> 11, l = mb & 2047;
        u16x4 pk;
        for (int r = 0; r < 4; ++r) pk[r] = f2h_bits(acc[i][j][r] + bv);
        *(u16x4*)(out + ((size_t)bb * 512 + n) * 2048 + l) = pk;
      }
    }
  }
}

// ---------------- kernel 4: flash cross-attention v8 -----------------------
// d-split decomposition (dd=2): each block = 128 queries x 256-wide d-half.
// 4 waves x 32 rows/wave, 256 threads, grid 512 (16 (b,tt) x 16 qtiles x 2
// d-halves), 1 block/CU, 1 wave/SIMD with a 512-reg budget.
// Why: v5 (310us) sat at EXACTLY the 256-reg cap (128 VGPR + 128 AGPR at
// 2 waves/SIMD) -> zero lookahead registers -> LDS latency exposure capped
// MfmaUtil at 18%. Here: qf 128 VGPR + acc 128 AGPR + temps ~ 335 of 512,
// leaving ~60 VGPRs of scheduling headroom. QK is duplicated across d-halves
// (+50% MFMA FLOP, cheap at 18% busy) but per-CU LDS traffic drops 512KB ->
// 200KB/iter (K amortized over 32 rows, V halved per block). K/V double-
// buffered, single end-of-iter barrier, wave-private P slab (no mid barrier).
__global__ __launch_bounds__(256, 1) void attn_kernel(const u16* __restrict__ qkv,
                                                      float* __restrict__ out) {
  const int t = threadIdx.x, lane = t & 63, w = t >> 6;  // w in 0..3
  const int ml = lane & 15, q = lane >> 4;
  // XCD swizzle: xcd = n&7 owns (b,tt) groups {2*xcd, 2*xcd+1}; 32 blocks/grp
  const int n = blockIdx.x;
  const int xcd = n & 7, slot = n >> 3;        // slot 0..63
  const int g = xcd * 2 + (slot >> 5);         // group 0..15
  const int inner = slot & 31;
  const int qt = inner & 15;                   // q-tile 0..15
  const int h = inner >> 4;                    // d-half 0..1
  const int b = g >> 1, tt = g & 1;

  const u16* Q  = qkv + (tt ? (size_t)3 * SZE : (size_t)0);
  const u16* K  = qkv + (tt ? (size_t)1 * SZE : (size_t)4 * SZE);
  const u16* Vt = qkv + (tt ? (size_t)5 * SZE : (size_t)2 * SZE);
  float* O = out + (tt ? (size_t)SZE : (size_t)0) +
             ((size_t)b * 2048 + qt * 128) * 512;
  const u16* Qb = Q + ((size_t)b * 2048 + qt * 128) * 512;
  const u16* Kb = K + (size_t)b * 2048 * 512;
  const u16* Vb = Vt + (size_t)b * 512 * 2048 + (size_t)h * 256 * 2048;  // [D][L]

  __shared__ u16 sK[2][16384];   // 2 x 32KB, chunk p: [dchunk(64)][key(32)]
  __shared__ u16 sV[2][8192];    // 2 x 16KB, chunk p: [kc(4)][d(256)]
  __shared__ u16 sP[4 * 1280];   // per-wave 32 rows x stride 40

  // Q A-frags for this wave's 32 rows (128 VGPR, resident all 64 iters)
  f16x8 qf0[16], qf1[16];
  {
    const u16* qrow0 = Qb + (size_t)(w * 32 + ml) * 512 + q * 8;
    const u16* qrow1 = qrow0 + 16 * 512;
#pragma unroll
    for (int ks = 0; ks < 16; ++ks) {
      qf0[ks] = *(const f16x8*)(qrow0 + ks * 32);
      qf1[ks] = *(const f16x8*)(qrow1 + ks * 32);
    }
  }

  fx4 acc0[16] = {}, acc1[16] = {};  // rows q*4+r of rowblock, col nj*16+ml
  fx4 mrun0 = {-3.0e38f, -3.0e38f, -3.0e38f, -3.0e38f};
  fx4 mrun1 = {-3.0e38f, -3.0e38f, -3.0e38f, -3.0e38f};
  fx4 lrun0 = {0.f, 0.f, 0.f, 0.f};
  fx4 lrun1 = {0.f, 0.f, 0.f, 0.f};
  u16* wp = sP + w * 1280;

  // prestage K[0] (8 rounds) and V-half[0] (4 rounds) into buffer 0
#pragma unroll
  for (int r = 0; r < 8; ++r) {
    int p = r * 256 + t;
    gl2lds16(Kb + (size_t)(p & 31) * 512 + (p >> 5) * 8, sK[0] + p * 8);
  }
#pragma unroll
  for (int r = 0; r < 4; ++r) {
    int p = r * 256 + t;
    gl2lds16(Vb + (size_t)(p & 255) * 2048 + (p >> 8) * 8, sV[0] + p * 8);
  }
  __syncthreads();

  for (int it = 0; it < 64; ++it) {
    const int c = it & 1;
    const int k0 = it * 32;
    const u16* sKc = sK[c];
    const u16* sVc = sV[c];
    // ---- stage K[it+1], V[it+1] into other buffer; drained at THIS iter's
    //      single end barrier (cover = entire iteration) ----
    if (it < 63) {
      const u16* Kn = Kb + (size_t)(k0 + 32) * 512;
      const u16* Vn = Vb + (size_t)(k0 + 32);
#pragma unroll
      for (int r = 0; r < 8; ++r) {
        int p = r * 256 + t;
        gl2lds16(Kn + (size_t)(p & 31) * 512 + (p >> 5) * 8, sK[c ^ 1] + p * 8);
      }
#pragma unroll
      for (int r = 0; r < 4; ++r) {
        int p = r * 256 + t;
        gl2lds16(Vn + (size_t)(p & 255) * 2048 + (p >> 8) * 8, sV[c ^ 1] + p * 8);
      }
    }
    // ---- QK^T: 32 rows x 32 keys, full D=512; each kf feeds 2 MFMAs ----
    fx4 s00 = {0.f, 0.f, 0.f, 0.f}, s01 = {0.f, 0.f, 0.f, 0.f};
    fx4 s10 = {0.f, 0.f, 0.f, 0.f}, s11 = {0.f, 0.f, 0.f, 0.f};
#pragma unroll
    for (int ks = 0; ks < 16; ++ks) {
      f16x8 kf0 = *(const f16x8*)(sKc + ((ks * 4 + q) * 32 + ml) * 8);
      f16x8 kf1 = *(const f16x8*)(sKc + ((ks * 4 + q) * 32 + 16 + ml) * 8);
      s00 = __builtin_amdgcn_mfma_f32_16x16x32_f16(qf0[ks], kf0, s00, 0, 0, 0);
      s01 = __builtin_amdgcn_mfma_f32_16x16x32_f16(qf0[ks], kf1, s01, 0, 0, 0);
      s10 = __builtin_amdgcn_mfma_f32_16x16x32_f16(qf1[ks], kf0, s10, 0, 0, 0);
      s11 = __builtin_amdgcn_mfma_f32_16x16x32_f16(qf1[ks], kf1, s11, 0, 0, 0);
    }
    // ---- online softmax, state in regs (rows = quad lanes q*4+r) ----
    bool need0 = false, need1 = false;
    fx4 al0, al1;
    {  // rowblock 0
      fx4 mx, sm;
#pragma unroll
      for (int r = 0; r < 4; ++r) mx[r] = fmaxf(s00[r], s01[r]);
#pragma unroll
      for (int d = 1; d < 16; d <<= 1) {
        mx[0] = fmaxf(mx[0], __shfl_xor(mx[0], d));
        mx[1] = fmaxf(mx[1], __shfl_xor(mx[1], d));
        mx[2] = fmaxf(mx[2], __shfl_xor(mx[2], d));
        mx[3] = fmaxf(mx[3], __shfl_xor(mx[3], d));
      }
#pragma unroll
      for (int r = 0; r < 4; ++r) {
        float mn = fmaxf(mrun0[r], mx[r]);
        al0[r] = __expf(mrun0[r] - mn);
        mrun0[r] = mn;
        s00[r] = __expf(s00[r] - mn);
        s01[r] = __expf(s01[r] - mn);
        sm[r] = s00[r] + s01[r];
        need0 |= (al0[r] != 1.0f);
      }
#pragma unroll
      for (int d = 1; d < 16; d <<= 1) {
        sm[0] += __shfl_xor(sm[0], d);
        sm[1] += __shfl_xor(sm[1], d);
        sm[2] += __shfl_xor(sm[2], d);
        sm[3] += __shfl_xor(sm[3], d);
      }
#pragma unroll
      for (int r = 0; r < 4; ++r) lrun0[r] = al0[r] * lrun0[r] + sm[r];
#pragma unroll
      for (int r = 0; r < 4; ++r) {
        wp[(q * 4 + r) * 40 + ml] = f2h_bits(s00[r]);
        wp[(q * 4 + r) * 40 + 16 + ml] = f2h_bits(s01[r]);
      }
    }
    {  // rowblock 1
      fx4 mx, sm;
#pragma unroll
      for (int r = 0; r < 4; ++r) mx[r] = fmaxf(s10[r], s11[r]);
#pragma unroll
      for (int d = 1; d < 16; d <<= 1) {
        mx[0] = fmaxf(mx[0], __shfl_xor(mx[0], d));
        mx[1] = fmaxf(mx[1], __shfl_xor(mx[1], d));
        mx[2] = fmaxf(mx[2], __shfl_xor(mx[2], d));
        mx[3] = fmaxf(mx[3], __shfl_xor(mx[3], d));
      }
#pragma unroll
      for (int r = 0; r < 4; ++r) {
        float mn = fmaxf(mrun1[r], mx[r]);
        al1[r] = __expf(mrun1[r] - mn);
        mrun1[r] = mn;
        s10[r] = __expf(s10[r] - mn);
        s11[r] = __expf(s11[r] - mn);
        sm[r] = s10[r] + s11[r];
        need1 |= (al1[r] != 1.0f);
      }
#pragma unroll
      for (int d = 1; d < 16; d <<= 1) {
        sm[0] += __shfl_xor(sm[0], d);
        sm[1] += __shfl_xor(sm[1], d);
        sm[2] += __shfl_xor(sm[2], d);
        sm[3] += __shfl_xor(sm[3], d);
      }
#pragma unroll
      for (int r = 0; r < 4; ++r) lrun1[r] = al1[r] * lrun1[r] + sm[r];
#pragma unroll
      for (int r = 0; r < 4; ++r) {
        wp[(16 + q * 4 + r) * 40 + ml] = f2h_bits(s10[r]);
        wp[(16 + q * 4 + r) * 40 + 16 + ml] = f2h_bits(s11[r]);
      }
    }
    // ---- rescale acc (per rowblock, skip when no row saw a new max);
    //      also covers the P ds_write -> pf ds_read latency ----
    if (__any(need0)) {
#pragma unroll
      for (int nj = 0; nj < 16; ++nj) {
        acc0[nj][0] *= al0[0]; acc0[nj][1] *= al0[1];
        acc0[nj][2] *= al0[2]; acc0[nj][3] *= al0[3];
      }
    }
    if (__any(need1)) {
#pragma unroll
      for (int nj = 0; nj < 16; ++nj) {
        acc1[nj][0] *= al1[0]; acc1[nj][1] *= al1[1];
        acc1[nj][2] *= al1[2]; acc1[nj][3] *= al1[3];
      }
    }
    // ---- P frags (wave-private slab: same-wave lgkm ordering, no barrier) --
    f16x8 pf0 = *(const f16x8*)(wp + ml * 40 + q * 8);
    f16x8 pf1 = *(const f16x8*)(wp + (16 + ml) * 40 + q * 8);
    // ---- PV over this block's 256 d; each vf feeds 2 MFMAs ----
#pragma unroll
    for (int nj = 0; nj < 16; ++nj) {
      f16x8 vf = *(const f16x8*)(sVc + (q * 256 + nj * 16 + ml) * 8);
      acc0[nj] = __builtin_amdgcn_mfma_f32_16x16x32_f16(pf0, vf, acc0[nj], 0, 0, 0);
      acc1[nj] = __builtin_amdgcn_mfma_f32_16x16x32_f16(pf1, vf, acc1[nj], 0, 0, 0);
    }
    __syncthreads();  // single barrier: drains next-iter staging + buffer flip
  }
  // ---- epilogue: O = acc / l (all wave-private) ----
  fx4 linv0, linv1;
#pragma unroll
  for (int r = 0; r < 4; ++r) {
    linv0[r] = 1.0f / lrun0[r];
    linv1[r] = 1.0f / lrun1[r];
  }
  float* Ob0 = O + (size_t)(w * 32 + q * 4) * 512 + h * 256 + ml;
  float* Ob1 = Ob0 + (size_t)16 * 512;
#pragma unroll
  for (int nj = 0; nj < 16; ++nj) {
#pragma unroll
    for (int r = 0; r < 4; ++r) {
      Ob0[(size_t)r * 512 + nj * 16] = acc0[nj][r] * linv0[r];
      Ob1[(size_t)r * 512 + nj * 16] = acc1[nj][r] * linv1[r];
    }
  }
}

extern "C" void kernel_launch(void* const* d_in, const int* in_sizes, int n_in,
                              void* d_out, int out_size, void* d_ws, size_t ws_size,
                              hipStream_t stream) {
  // ws layout (u16 elems): [xh: 2*SZE][wt: 6*512*512][qkv: 6*SZE]
  //   qkv order: 0=Qr 1=Kr 2=Vr^T 3=Qh 4=Kh 5=Vh^T
  u16* ws = (u16*)d_ws;
  u16* xh = ws;
  u16* wt = ws + 16777216u;            // 2*SZE
  u16* qkv = ws + 18350080u;           // 2*SZE + 6*262144

  convert_x<<<8192, 256, 0, stream>>>((const float*)d_in[0],
                                      (const float*)d_in[1], xh);
  wtrans<<<dim3(16, 16, 6), dim3(32, 8), 0, stream>>>(
      (const float*)d_in[2], (const float*)d_in[4], (const float*)d_in[6],
      (const float*)d_in[8], (const float*)d_in[10], (const float*)d_in[12], wt);
  proj_gemm<<<dim3(128, 4, 6), 256, 0, stream>>>(
      xh, wt, qkv,
      (const float*)d_in[3], (const float*)d_in[5], (const float*)d_in[7],
      (const float*)d_in[9], (const float*)d_in[11], (const float*)d_in[13]);
  attn_kernel<<<512, 256, 0, stream>>>(qkv, (float*)d_out);
}

// Round 4
// 570.419 us; speedup vs baseline: 2.3421x; 1.3984x over previous
//
#include <hip/hip_runtime.h>

typedef unsigned short u16;
typedef _Float16 f16;
typedef __attribute__((ext_vector_type(8))) f16 f16x8;
typedef __attribute__((ext_vector_type(4))) float fx4;
typedef __attribute__((ext_vector_type(8))) u16 u16x8;
typedef __attribute__((ext_vector_type(4))) u16 u16x4;

#define SZE 8388608u  // 16384*512 elements per [B*L, D] matrix

__device__ __forceinline__ u16 f2h_bits(float x) {
  union { f16 h; u16 u; } v; v.h = (f16)x; return v.u;
}

// async global->LDS, 16B per lane; dest is wave-uniform base + lane*16.
__device__ __forceinline__ void gl2lds16(const void* g, void* l) {
  __builtin_amdgcn_global_load_lds(
      (const __attribute__((address_space(1))) unsigned int*)g,
      (__attribute__((address_space(3))) unsigned int*)l, 16, 0, 0);
}

// ---- DPP 16-lane all-reduce (VALU only; replaces ds_swizzle shfl chains) --
// xor1 = quad_perm[1,0,3,2] (0xB1), xor2 = quad_perm[2,3,0,1] (0x4E).
// After those two, values are quad-uniform, so row_half_mirror (0x141, ^7)
// acts as xor4 and row_mirror (0x140, ^15) acts as xor8.
template <int C>
__device__ __forceinline__ float dppf(float x) {
  return __int_as_float(__builtin_amdgcn_update_dpp(
      __float_as_int(x), __float_as_int(x), C, 0xf, 0xf, false));
}
__device__ __forceinline__ float rowmax16(float x) {
  x = fmaxf(x, dppf<0xB1>(x));
  x = fmaxf(x, dppf<0x4E>(x));
  x = fmaxf(x, dppf<0x141>(x));
  x = fmaxf(x, dppf<0x140>(x));
  return x;
}
__device__ __forceinline__ float rowsum16(float x) {
  x += dppf<0xB1>(x);
  x += dppf<0x4E>(x);
  x += dppf<0x141>(x);
  x += dppf<0x140>(x);
  return x;
}

// ---------------- kernel 1: fp32 -> fp16 convert of both inputs ------------
__global__ __launch_bounds__(256) void convert_x(const float* __restrict__ x0,
                                                 const float* __restrict__ x1,
                                                 u16* __restrict__ xh) {
  size_t i = ((size_t)blockIdx.x * 256 + threadIdx.x) * 8;
  const float* src = (i < SZE) ? (x0 + i) : (x1 + (i - SZE));
  float4 a = *(const float4*)(src);
  float4 b = *(const float4*)(src + 4);
  u16x8 o;
  o[0] = f2h_bits(a.x); o[1] = f2h_bits(a.y);
  o[2] = f2h_bits(a.z); o[3] = f2h_bits(a.w);
  o[4] = f2h_bits(b.x); o[5] = f2h_bits(b.y);
  o[6] = f2h_bits(b.z); o[7] = f2h_bits(b.w);
  *(u16x8*)(xh + i) = o;
}

// ---------------- kernel 2: W [K][N] fp32 -> Wt [N][K] fp16 ----------------
__global__ __launch_bounds__(256) void wtrans(
    const float* __restrict__ w0, const float* __restrict__ w1,
    const float* __restrict__ w2, const float* __restrict__ w3,
    const float* __restrict__ w4, const float* __restrict__ w5,
    u16* __restrict__ wt) {
  __shared__ float tile[32][33];
  const int z = blockIdx.z;
  const float* W = z == 0 ? w0 : z == 1 ? w1 : z == 2 ? w2
                 : z == 3 ? w3 : z == 4 ? w4 : w5;
  u16* WT = wt + (size_t)z * 262144u;
  const int k0 = blockIdx.x * 32, n0 = blockIdx.y * 32;
  const int tx = threadIdx.x, ty = threadIdx.y;  // 32 x 8
  for (int j = 0; j < 32; j += 8)
    tile[ty + j][tx] = W[(size_t)(k0 + ty + j) * 512 + n0 + tx];
  __syncthreads();
  for (int j = 0; j < 32; j += 8)
    WT[(size_t)(n0 + ty + j) * 512 + k0 + tx] = f2h_bits(tile[tx][ty + j]);
}

// ---------------- kernel 3: six projections, C = X*W + b -------------------
__global__ __launch_bounds__(256, 2) void proj_gemm(
    const u16* __restrict__ xh, const u16* __restrict__ wt,
    u16* __restrict__ qkv,
    const float* __restrict__ b0, const float* __restrict__ b1,
    const float* __restrict__ b2, const float* __restrict__ b3,
    const float* __restrict__ b4, const float* __restrict__ b5) {
  const int proj = blockIdx.z;
  const u16* X = xh + (proj < 3 ? 0u : SZE);
  const u16* W = wt + (size_t)proj * 262144u;
  u16* out = qkv + (size_t)proj * SZE;
  const float* bias = proj == 0 ? b0 : proj == 1 ? b1 : proj == 2 ? b2
                    : proj == 3 ? b3 : proj == 4 ? b4 : b5;
  const int m0 = blockIdx.x * 128, n0 = blockIdx.y * 128;
  const int t = threadIdx.x, lane = t & 63, w = t >> 6;
  const int wr = w >> 1, wc = w & 1, ml = lane & 15, q = lane >> 4;
  __shared__ u16 sA[4096], sB[4096];
  fx4 acc[4][4] = {};
  for (int k0 = 0; k0 < 512; k0 += 32) {
    for (int r = 0; r < 2; ++r) {
      int c = r * 256 + t;
      int cq = c >> 7, cm = c & 127;
      gl2lds16(X + (size_t)(m0 + cm) * 512 + (k0 + cq * 8), sA + c * 8);
      gl2lds16(W + (size_t)(n0 + cm) * 512 + (k0 + cq * 8), sB + c * 8);
    }
    __syncthreads();
    f16x8 af[4], bf[4];
    for (int i = 0; i < 4; ++i) {
      af[i] = *(const f16x8*)(sA + (q * 128 + wr * 64 + i * 16 + ml) * 8);
      bf[i] = *(const f16x8*)(sB + (q * 128 + wc * 64 + i * 16 + ml) * 8);
    }
    for (int i = 0; i < 4; ++i)
      for (int j = 0; j < 4; ++j)
        acc[i][j] = __builtin_amdgcn_mfma_f32_16x16x32_f16(af[i], bf[j],
                                                           acc[i][j], 0, 0, 0);
    __syncthreads();
  }
  const bool vtrans = (proj % 3) == 2;
  for (int j = 0; j < 4; ++j) {
    const int n = n0 + wc * 64 + j * 16 + ml;
    const float bv = bias[n];
    for (int i = 0; i < 4; ++i) {
      const int mb = m0 + wr * 64 + i * 16 + q * 4;
      if (!vtrans) {
        for (int r = 0; r < 4; ++r)
          out[(size_t)(mb + r) * 512 + n] = f2h_bits(acc[i][j][r] + bv);
      } else {
        const int bb = mb >> 11, l = mb & 2047;
        u16x4 pk;
        for (int r = 0; r < 4; ++r) pk[r] = f2h_bits(acc[i][j][r] + bv);
        *(u16x4*)(out + ((size_t)bb * 512 + n) * 2048 + l) = pk;
      }
    }
  }
}

// ---------------- kernel 4: flash cross-attention v9 -----------------------
// v5 structure (proven 310us: 8 waves x 16 rows, K/V dbuf, single barrier)
// with chain-shortening + de-phasing, zero register cost:
//  (1) softmax reduces via DPP (VALU) instead of __shfl_xor (ds_swizzle):
//      removes 32 LDS-pipe ops/wave/iter and ~2/3 of the reduce latency.
//  (2) deferred rescale, THR=10: skip max-update+rescale while the new tile
//      max is within 10 of the running max (P <= e^10 = 22026 fits f16).
//  (3) P writes issued right after exp; sum-reduce+lrun cover the
//      write->read LDS latency.
//  (4) odd/even waves run QK and PV half-loops in swapped order (static
//      indices only) + s_setprio(1) around MFMA clusters: de-correlates
//      the post-barrier LDS/MFMA bursts of the 2 waves sharing a SIMD.
__global__ __launch_bounds__(512, 2) void attn_kernel(const u16* __restrict__ qkv,
                                                      float* __restrict__ out) {
  const int t = threadIdx.x, lane = t & 63, w = t >> 6;  // w in 0..7
  const int ml = lane & 15, q = lane >> 4;
  // XCD swizzle: xcd = n&7 owns (b,tt) groups {2*xcd, 2*xcd+1}
  const int n = blockIdx.x;
  const int xcd = n & 7, slot = n >> 3;
  const int g = xcd * 2 + (slot >> 4);
  const int qt = slot & 15;
  const int b = g >> 1, tt = g & 1;

  const u16* Q  = qkv + (tt ? (size_t)3 * SZE : (size_t)0);
  const u16* K  = qkv + (tt ? (size_t)1 * SZE : (size_t)4 * SZE);
  const u16* Vt = qkv + (tt ? (size_t)5 * SZE : (size_t)2 * SZE);
  float* O = out + (tt ? (size_t)SZE : (size_t)0) +
             ((size_t)b * 2048 + qt * 128) * 512;
  const u16* Qb = Q + ((size_t)b * 2048 + qt * 128) * 512;
  const u16* Kb = K + (size_t)b * 2048 * 512;
  const u16* Vb = Vt + (size_t)b * 512 * 2048;  // [D][L]

  __shared__ u16 sK[2][16384];   // 2 x 32KB, chunk p: [dchunk(64)][key(32)]
  __shared__ u16 sV[2][16384];   // 2 x 32KB, chunk p: [kc(4)][d(512)]
  __shared__ u16 sP[8 * 640];    // per-wave 16 rows x stride 40

  // Q A-frags for this wave's 16 rows (64 VGPR, resident all 64 iters)
  f16x8 qf[16];
  {
    const u16* qrow = Qb + (size_t)(w * 16 + ml) * 512 + q * 8;
#pragma unroll
    for (int ks = 0; ks < 16; ++ks) qf[ks] = *(const f16x8*)(qrow + ks * 32);
  }

  fx4 acc[32] = {};  // rows q*4+r (of wave's 16), col nj*16+ml  (128 VGPR)
  fx4 mrun = {-3.0e38f, -3.0e38f, -3.0e38f, -3.0e38f};
  fx4 lrun = {0.f, 0.f, 0.f, 0.f};
  u16* wp = sP + w * 640;
  const bool odd = (w & 1);

  // prestage K[0], V[0] into buffer 0
#pragma unroll
  for (int r = 0; r < 4; ++r) {
    int p = r * 512 + t;
    gl2lds16(Kb + (size_t)(p & 31) * 512 + (p >> 5) * 8, sK[0] + p * 8);
    gl2lds16(Vb + (size_t)(p & 511) * 2048 + (p >> 9) * 8, sV[0] + p * 8);
  }
  __syncthreads();

  for (int it = 0; it < 64; ++it) {
    const int c = it & 1;
    const int k0 = it * 32;
    const u16* sKc = sK[c];
    const u16* sVc = sV[c];
    // ---- stage K[it+1], V[it+1] into other buffer; drained at THIS iter's
    //      single end barrier (cover = entire iteration) ----
    if (it < 63) {
      const u16* Kn = Kb + (size_t)(k0 + 32) * 512;
      const u16* Vn = Vb + (size_t)(k0 + 32);
#pragma unroll
      for (int r = 0; r < 4; ++r) {
        int p = r * 512 + t;
        gl2lds16(Kn + (size_t)(p & 31) * 512 + (p >> 5) * 8, sK[c ^ 1] + p * 8);
        gl2lds16(Vn + (size_t)(p & 511) * 2048 + (p >> 9) * 8, sV[c ^ 1] + p * 8);
      }
    }
    // ---- QK^T: this wave's 16 rows x 32 keys; halves in wave-swapped order
    fx4 s0 = {0.f, 0.f, 0.f, 0.f}, s1 = {0.f, 0.f, 0.f, 0.f};
    __builtin_amdgcn_s_setprio(1);
#define QK8(B)                                                               \
  _Pragma("unroll") for (int ks = (B); ks < (B) + 8; ++ks) {                 \
    f16x8 kf0 = *(const f16x8*)(sKc + ((ks * 4 + q) * 32 + ml) * 8);         \
    f16x8 kf1 = *(const f16x8*)(sKc + ((ks * 4 + q) * 32 + 16 + ml) * 8);    \
    s0 = __builtin_amdgcn_mfma_f32_16x16x32_f16(qf[ks], kf0, s0, 0, 0, 0);   \
    s1 = __builtin_amdgcn_mfma_f32_16x16x32_f16(qf[ks], kf1, s1, 0, 0, 0);   \
  }
    if (odd) { QK8(8) QK8(0) } else { QK8(0) QK8(8) }
#undef QK8
    __builtin_amdgcn_s_setprio(0);
    // ---- online softmax, state in regs; DPP reduces (no LDS pipe) ----
    fx4 mx, alpha = {1.f, 1.f, 1.f, 1.f}, p0, p1, sm;
#pragma unroll
    for (int r = 0; r < 4; ++r) mx[r] = rowmax16(fmaxf(s0[r], s1[r]));
    bool nd = false;
#pragma unroll
    for (int r = 0; r < 4; ++r) nd |= (mx[r] > mrun[r] + 10.0f);
    const bool need = __any(nd);
    if (need) {  // wave-uniform
#pragma unroll
      for (int r = 0; r < 4; ++r) {
        float mn = fmaxf(mrun[r], mx[r]);
        alpha[r] = __expf(mrun[r] - mn);
        mrun[r] = mn;
      }
    }
#pragma unroll
    for (int r = 0; r < 4; ++r) {
      p0[r] = __expf(s0[r] - mrun[r]);  // bounded by e^10 when deferred
      p1[r] = __expf(s1[r] - mrun[r]);
    }
    // ---- P -> wave-private slab immediately (same-wave lgkm ordering);
    //      the sum-reduce + lrun update below covers the write->read gap ----
#pragma unroll
    for (int r = 0; r < 4; ++r) {
      wp[(q * 4 + r) * 40 + ml] = f2h_bits(p0[r]);
      wp[(q * 4 + r) * 40 + 16 + ml] = f2h_bits(p1[r]);
    }
#pragma unroll
    for (int r = 0; r < 4; ++r) sm[r] = rowsum16(p0[r] + p1[r]);
#pragma unroll
    for (int r = 0; r < 4; ++r) lrun[r] = alpha[r] * lrun[r] + sm[r];
    // ---- rescale acc only when the running max actually moved ----
    if (need) {
#pragma unroll
      for (int nj = 0; nj < 32; ++nj) {
        acc[nj][0] *= alpha[0]; acc[nj][1] *= alpha[1];
        acc[nj][2] *= alpha[2]; acc[nj][3] *= alpha[3];
      }
    }
    f16x8 pf = *(const f16x8*)(wp + ml * 40 + q * 8);
    // ---- PV over all 512 d; halves in wave-swapped order ----
    __builtin_amdgcn_s_setprio(1);
#define PV16(B)                                                              \
  _Pragma("unroll") for (int nj = (B); nj < (B) + 16; ++nj) {                \
    f16x8 vf = *(const f16x8*)(sVc + (q * 512 + nj * 16 + ml) * 8);          \
    acc[nj] = __builtin_amdgcn_mfma_f32_16x16x32_f16(pf, vf, acc[nj], 0, 0, 0); \
  }
    if (odd) { PV16(16) PV16(0) } else { PV16(0) PV16(16) }
#undef PV16
    __builtin_amdgcn_s_setprio(0);
    __syncthreads();  // single barrier: drains next-iter staging + buffer flip
  }
  // ---- epilogue: O = acc / l (all wave-private) ----
  fx4 linv;
#pragma unroll
  for (int r = 0; r < 4; ++r) linv[r] = 1.0f / lrun[r];
  float* Ob = O + (size_t)(w * 16 + q * 4) * 512 + ml;
#pragma unroll
  for (int nj = 0; nj < 32; ++nj) {
#pragma unroll
    for (int r = 0; r < 4; ++r)
      Ob[(size_t)r * 512 + nj * 16] = acc[nj][r] * linv[r];
  }
}

extern "C" void kernel_launch(void* const* d_in, const int* in_sizes, int n_in,
                              void* d_out, int out_size, void* d_ws, size_t ws_size,
                              hipStream_t stream) {
  // ws layout (u16 elems): [xh: 2*SZE][wt: 6*512*512][qkv: 6*SZE]
  //   qkv order: 0=Qr 1=Kr 2=Vr^T 3=Qh 4=Kh 5=Vh^T
  u16* ws = (u16*)d_ws;
  u16* xh = ws;
  u16* wt = ws + 16777216u;            // 2*SZE
  u16* qkv = ws + 18350080u;           // 2*SZE + 6*262144

  convert_x<<<8192, 256, 0, stream>>>((const float*)d_in[0],
                                      (const float*)d_in[1], xh);
  wtrans<<<dim3(16, 16, 6), dim3(32, 8), 0, stream>>>(
      (const float*)d_in[2], (const float*)d_in[4], (const float*)d_in[6],
      (const float*)d_in[8], (const float*)d_in[10], (const float*)d_in[12], wt);
  proj_gemm<<<dim3(128, 4, 6), 256, 0, stream>>>(
      xh, wt, qkv,
      (const float*)d_in[3], (const float*)d_in[5], (const float*)d_in[7],
      (const float*)d_in[9], (const float*)d_in[11], (const float*)d_in[13]);
  attn_kernel<<<256, 512, 0, stream>>>(qkv, (float*)d_out);
}